// Round 11
// baseline (131.425 us; speedup 1.0000x reference)
//
#include <hip/hip_runtime.h>
#include <hip/hip_bf16.h>

#define BATCH 4096
#define NTOT  8192
#define DIM   512
#define NTILE 2080  // triangle over 64x64 grid of 128-tiles
#define NBLK  2048  // 2048 = 4 exact rounds at 2 blocks/CU; blocks<32 do 2 tiles

typedef __attribute__((ext_vector_type(8))) __bf16 bf16x8;
typedef __attribute__((ext_vector_type(4))) float  floatx4;

__device__ __forceinline__ unsigned short f2bf(float x) {
  union { float f; unsigned u; } v; v.f = x;
  unsigned r = v.u + 0x7fffu + ((v.u >> 16) & 1u);   // RNE
  return (unsigned short)(r >> 16);
}

#define ASYNC16(gp, lp)                                                        \
  __builtin_amdgcn_global_load_lds(                                            \
      (__attribute__((address_space(1))) void*)(gp),                           \
      (__attribute__((address_space(3))) void*)(lp), 16, 0, 0)

// ---------------------------------------------------------------- normalize
// One wave per row: read 512 fp32, rsqrt(sum sq), write 512 bf16.
// Blocks 0..31 also zero S; block 32 zeroes out[0] (loss accumulates into it).
__global__ __launch_bounds__(256) void nrm_kernel(const float* __restrict__ zi,
                                                  const float* __restrict__ zj,
                                                  ushort* __restrict__ zn,
                                                  float* __restrict__ S,
                                                  float* __restrict__ out) {
  if (blockIdx.x < 32) S[blockIdx.x * 256 + threadIdx.x] = 0.0f;
  if (blockIdx.x == 32 && threadIdx.x == 0) out[0] = 0.0f;
  const int row = blockIdx.x * 4 + (threadIdx.x >> 6);
  const int l   = threadIdx.x & 63;
  const float* src = (row < BATCH) ? (zi + (size_t)row * DIM)
                                   : (zj + (size_t)(row - BATCH) * DIM);
  const float4* s4 = (const float4*)src;
  float4 v0 = s4[l];
  float4 v1 = s4[l + 64];
  float ss = v0.x*v0.x + v0.y*v0.y + v0.z*v0.z + v0.w*v0.w
           + v1.x*v1.x + v1.y*v1.y + v1.z*v1.z + v1.w*v1.w;
  #pragma unroll
  for (int m = 1; m < 64; m <<= 1) ss += __shfl_xor(ss, m, 64);
  const float r = 1.0f / fmaxf(sqrtf(ss), 1e-12f);
  ushort4 o0, o1;
  o0.x = f2bf(v0.x * r); o0.y = f2bf(v0.y * r);
  o0.z = f2bf(v0.z * r); o0.w = f2bf(v0.w * r);
  o1.x = f2bf(v1.x * r); o1.y = f2bf(v1.y * r);
  o1.z = f2bf(v1.z * r); o1.w = f2bf(v1.w * r);
  ushort4* d4 = (ushort4*)(zn + (size_t)row * DIM);
  d4[l]      = o0;
  d4[l + 64] = o1;
}

// ---------------------------------------------------------------- main GEMM
// EXACT R5 128x128 body (proven 55.5-56.2us), wrapped in a rep loop that
// fixes GRID QUANTIZATION: 2080 tiles on 512 CU-slots = 4.06 rounds, which
// previously executed as ~5 rounds (last 32 blocks ran nearly alone, ~10us
// tail). Now 2048 blocks; blocks 0..31 process tiles {b, 2048+b} (dispatched
// first, so the extra tiles overlap rounds 2-4), blocks 32..2047 one tile.
// nrep is uniform per block -> barriers legal. The epilogue __syncthreads
// (before the S atomics) already fences last LDS reads of rep 0 against
// rep 1's STAGE writes; the K-loop's first __syncthreads drains its vmcnt.
// Lessons pinned: 256² tile = 1 block/CU -> lost cross-block overlap + 3-round
// quantization, net loss (R10). Rule #20: no runtime array index into acc
// (R8/R9, 2.29GB spill). NO fused loss tail (+15us R3/R4). NO agent ACQ_REL
// (+25us R1/R2). NO XCD swizzle. NO sched_barrier pinning (R1/m141).
// Depth-2 prefetch null (R6). BK=64 regression (R7).
__global__ __launch_bounds__(256) void simsum_kernel(const ushort* __restrict__ zn,
                                                     float* __restrict__ S,
                                                     float* __restrict__ P) {
  __shared__ __align__(16) ushort shA[2 * 4096];
  __shared__ __align__(16) ushort shB[2 * 4096];
  __shared__ float redR[2][128];
  __shared__ float redC[2][128];

  const int b    = blockIdx.x;
  const int nrep = (b < NTILE - NBLK) ? 2 : 1;

  const int t    = threadIdx.x;
  const int w    = t >> 6;
  const int l    = t & 63;
  const int quad = l >> 4;
  const int lo   = l & 15;
  const int wm   = w >> 1;
  const int wn   = w & 1;

  for (int rep = 0; rep < nrep; ++rep) {
    const int u = (rep == 0) ? b : (NBLK + b);
    // triangle decode: u = bj*(bj+1)/2 + bi, bi <= bj < 64
    int bj = (int)((sqrtf(8.0f * (float)u + 1.0f) - 1.0f) * 0.5f);
    while ((bj + 1) * (bj + 2) / 2 <= u) ++bj;
    while (bj * (bj + 1) / 2 > u) --bj;
    const int bi = u - bj * (bj + 1) / 2;
    const bool diag = (bi == bj);
    const bool posb = (bj == bi + BATCH / 128);
    const int tileRow = bi * 128;
    const int tileCol = bj * 128;

    // staging: lane l of wave w stages chunks c0 = w*128+l and c1 = c0+64
    // into LDS at chunk*16B (wave-uniform base + lane*16). Source k-chunk
    // XOR-swizzled.
    const int c0 = w * 128 + l;
    const int c1 = c0 + 64;
    const int r0 = c0 >> 2, k0 = ((c0 & 3) ^ ((r0 >> 1) & 3)) * 8;
    const int r1 = c1 >> 2, k1 = ((c1 & 3) ^ ((r1 >> 1) & 3)) * 8;
    const ushort* gA0 = zn + (size_t)(tileRow + r0) * DIM + k0;
    const ushort* gA1 = zn + (size_t)(tileRow + r1) * DIM + k1;
    const ushort* gB0 = zn + (size_t)(tileCol + r0) * DIM + k0;
    const ushort* gB1 = zn + (size_t)(tileCol + r1) * DIM + k1;
    ushort* lA0 = shA + w * 1024;
    ushort* lA1 = shA + w * 1024 + 512;
    ushort* lB0 = shB + w * 1024;
    ushort* lB1 = shB + w * 1024 + 512;

    floatx4 acc[4][4];
    #pragma unroll
    for (int i = 0; i < 4; ++i)
      #pragma unroll
      for (int j = 0; j < 4; ++j)
        acc[i][j] = (floatx4){0.f, 0.f, 0.f, 0.f};

    // fragment read offsets (ushorts): chunk = R*4 + (quad ^ ((lo>>1)&3))
    const int sw   = (quad ^ ((lo >> 1) & 3)) * 8;
    const int aOff = (wm * 64 + lo) * 32 + sw;  // + i*512
    const int bOff = (wn * 64 + lo) * 32 + sw;  // + j*512

    // prologue: stage K-tile 0 into buffer 0
    ASYNC16(gA0, lA0); ASYNC16(gA1, lA1);
    ASYNC16(gB0, lB0); ASYNC16(gB1, lB1);
    gA0 += 32; gA1 += 32; gB0 += 32; gB1 += 32;

    #pragma unroll
    for (int it = 0; it < 16; ++it) {
      __syncthreads();  // drains loads for buffer `cur` (issued one iter ago)
      const int co = (it & 1) * 4096;
      const int no = co ^ 4096;
      if (it < 15) {
        ASYNC16(gA0, lA0 + no); ASYNC16(gA1, lA1 + no);
        ASYNC16(gB0, lB0 + no); ASYNC16(gB1, lB1 + no);
        gA0 += 32; gA1 += 32; gB0 += 32; gB1 += 32;
      }
      bf16x8 aF[4], bF[4];
      #pragma unroll
      for (int i = 0; i < 4; ++i) aF[i] = *(const bf16x8*)(shA + co + aOff + i * 512);
      #pragma unroll
      for (int j = 0; j < 4; ++j) bF[j] = *(const bf16x8*)(shB + co + bOff + j * 512);
      #pragma unroll
      for (int i = 0; i < 4; ++i)
        #pragma unroll
        for (int j = 0; j < 4; ++j)
          acc[i][j] = __builtin_amdgcn_mfma_f32_16x16x32_bf16(aF[i], bF[j],
                                                              acc[i][j], 0, 0, 0);
    }

    // ---- epilogue. C/D layout: col = lo, row = quad*4 + r (within 16x16)
    float rs[4][4];
    float cs[4];
    #pragma unroll
    for (int i = 0; i < 4; ++i)
      #pragma unroll
      for (int r = 0; r < 4; ++r) rs[i][r] = 0.f;
    #pragma unroll
    for (int j = 0; j < 4; ++j) cs[j] = 0.f;

    #pragma unroll
    for (int i = 0; i < 4; ++i)
      #pragma unroll
      for (int j = 0; j < 4; ++j)
        #pragma unroll
        for (int r = 0; r < 4; ++r) {
          const float e = __expf(acc[i][j][r] * 10.0f - 10.0f);
          rs[i][r] += e;
          cs[j] += e;
        }

    // block-local diagonal lanes: wm==wn, lo == quad*4 + r (quad == lo>>2)
    if (wm == wn && quad == (lo >> 2)) {
      const int r = lo & 3;
      if (diag) {  // self-similarity: remove exp from both row and col sums
        #pragma unroll
        for (int i = 0; i < 4; ++i) {
          const float e = __expf(acc[i][i][r] * 10.0f - 10.0f);
          rs[i][r] -= e;
          cs[i] -= e;
        }
      }
      if (posb) {  // positives: col == row + BATCH
        #pragma unroll
        for (int i = 0; i < 4; ++i) {
          const int row = tileRow + wm * 64 + i * 16 + lo;
          const float v = acc[i][i][r] * 10.0f;
          P[row] = v;
          P[row + BATCH] = v;
        }
      }
    }

    // row sums: reduce across the 16 column-lanes (low 4 lane bits)
    #pragma unroll
    for (int m = 1; m < 16; m <<= 1) {
      #pragma unroll
      for (int i = 0; i < 4; ++i)
        #pragma unroll
        for (int r = 0; r < 4; ++r)
          rs[i][r] += __shfl_xor(rs[i][r], m, 64);
    }
    if (lo == 0) {
      #pragma unroll
      for (int i = 0; i < 4; ++i)
        #pragma unroll
        for (int r = 0; r < 4; ++r)
          redR[wn][wm * 64 + i * 16 + quad * 4 + r] = rs[i][r];
    }
    // col sums: reduce across the 4 quads (lane bits 4,5)
    #pragma unroll
    for (int m = 16; m < 64; m <<= 1) {
      #pragma unroll
      for (int j = 0; j < 4; ++j) cs[j] += __shfl_xor(cs[j], m, 64);
    }
    if (quad == 0) {
      #pragma unroll
      for (int j = 0; j < 4; ++j)
        redC[wm][wn * 64 + j * 16 + lo] = cs[j];
    }
    __syncthreads();   // also fences rep's LDS reads vs next rep's staging
    if (t < 128) {
      atomicAdd(&S[tileRow + t], redR[0][t] + redR[1][t]);
    } else if (!diag) {
      const int c = t - 128;
      atomicAdd(&S[tileCol + c], redC[0][c] + redC[1][c]);
    }
    // fire-and-forget atomics; next rep (if any) restages immediately.
  }
}

// ---------------------------------------------------------------- final loss
// 32 blocks x 256 threads, 1 element/thread; partial per block, one float
// atomicAdd into out[0] (zeroed by nrm).
__global__ __launch_bounds__(256) void loss_kernel(const float* __restrict__ S,
                                                   const float* __restrict__ P,
                                                   float* __restrict__ out) {
  const int i = blockIdx.x * 256 + threadIdx.x;
  float a = 10.0f + logf(S[i]) - P[i];
  #pragma unroll
  for (int m = 1; m < 64; m <<= 1) a += __shfl_xor(a, m, 64);
  __shared__ float sb[4];
  if ((threadIdx.x & 63) == 0) sb[threadIdx.x >> 6] = a;
  __syncthreads();
  if (threadIdx.x == 0)
    atomicAdd(out, (sb[0] + sb[1] + sb[2] + sb[3]) * (1.0f / (float)NTOT));
}

extern "C" void kernel_launch(void* const* d_in, const int* in_sizes, int n_in,
                              void* d_out, int out_size, void* d_ws, size_t ws_size,
                              hipStream_t stream) {
  const float* zi = (const float*)d_in[0];
  const float* zj = (const float*)d_in[1];
  ushort* zn = (ushort*)d_ws;                                  // 8192*512 bf16 = 8 MB
  float*  S  = (float*)((char*)d_ws + (size_t)NTOT * DIM * 2); // 32 KB
  float*  P  = S + NTOT;                                       // 32 KB
  float*  out = (float*)d_out;

  nrm_kernel<<<NTOT / 4, 256, 0, stream>>>(zi, zj, zn, S, out);
  simsum_kernel<<<NBLK, 256, 0, stream>>>(zn, S, P);
  loss_kernel<<<NTOT / 256, 256, 0, stream>>>(S, P, out);
}

// Round 12
// 119.333 us; speedup vs baseline: 1.1013x; 1.1013x over previous
//
#include <hip/hip_runtime.h>
#include <hip/hip_bf16.h>

#define BATCH 4096
#define NTOT  8192
#define DIM   512
#define NBLK  2080

typedef __attribute__((ext_vector_type(8))) __bf16 bf16x8;
typedef __attribute__((ext_vector_type(4))) float  floatx4;

__device__ __forceinline__ unsigned short f2bf(float x) {
  union { float f; unsigned u; } v; v.f = x;
  unsigned r = v.u + 0x7fffu + ((v.u >> 16) & 1u);   // RNE
  return (unsigned short)(r >> 16);
}

#define ASYNC16(gp, lp)                                                        \
  __builtin_amdgcn_global_load_lds(                                            \
      (__attribute__((address_space(1))) void*)(gp),                           \
      (__attribute__((address_space(3))) void*)(lp), 16, 0, 0)

// ---------------------------------------------------------------- normalize
// One wave per row: read 512 fp32, rsqrt(sum sq), write 512 bf16.
// Blocks 0..31 also zero S; block 32 zeroes out[0] (loss accumulates into it).
__global__ __launch_bounds__(256) void nrm_kernel(const float* __restrict__ zi,
                                                  const float* __restrict__ zj,
                                                  ushort* __restrict__ zn,
                                                  float* __restrict__ S,
                                                  float* __restrict__ out) {
  if (blockIdx.x < 32) S[blockIdx.x * 256 + threadIdx.x] = 0.0f;
  if (blockIdx.x == 32 && threadIdx.x == 0) out[0] = 0.0f;
  const int row = blockIdx.x * 4 + (threadIdx.x >> 6);
  const int l   = threadIdx.x & 63;
  const float* src = (row < BATCH) ? (zi + (size_t)row * DIM)
                                   : (zj + (size_t)(row - BATCH) * DIM);
  const float4* s4 = (const float4*)src;
  float4 v0 = s4[l];
  float4 v1 = s4[l + 64];
  float ss = v0.x*v0.x + v0.y*v0.y + v0.z*v0.z + v0.w*v0.w
           + v1.x*v1.x + v1.y*v1.y + v1.z*v1.z + v1.w*v1.w;
  #pragma unroll
  for (int m = 1; m < 64; m <<= 1) ss += __shfl_xor(ss, m, 64);
  const float r = 1.0f / fmaxf(sqrtf(ss), 1e-12f);
  ushort4 o0, o1;
  o0.x = f2bf(v0.x * r); o0.y = f2bf(v0.y * r);
  o0.z = f2bf(v0.z * r); o0.w = f2bf(v0.w * r);
  o1.x = f2bf(v1.x * r); o1.y = f2bf(v1.y * r);
  o1.z = f2bf(v1.z * r); o1.w = f2bf(v1.w * r);
  ushort4* d4 = (ushort4*)(zn + (size_t)row * DIM);
  d4[l]      = o0;
  d4[l + 64] = o1;
}

// ---------------------------------------------------------------- main GEMM
// EXACT R5 body (proven 55.5-56.2us) with ONE change: __launch_bounds__(256,3)
// requests 3 waves/EU = 3 blocks/CU (was 2). Mechanism: no single pipe is
// >36% busy (MFMA 24, VALU 22, LDS ~36, HBM 19) — pipes are serialized by the
// barrier-locked cadence; a third phase-skewed block adds cross-block overlap
// (m114). Register math: 84 VGPR + 64 AGPR = 148/wave <= 170 cap at 3 w/EU,
// no spill expected. LDS 34.8KB x 3 = 104KB <= 160KB.
// Lessons pinned: rep-loop grid repack = codegen regression (R11). 256² tile
// = 1 block/CU, net loss (R10). Rule #20: no runtime array index into acc
// (R8/R9, 2.29GB spill). NO fused loss tail (+15us R3/R4). NO agent ACQ_REL
// (+25us R1/R2). NO XCD swizzle. NO sched_barrier pinning (R1/m141).
// Depth-2 prefetch null (R6). BK=64 regression (R7).
__global__ __launch_bounds__(256, 3) void simsum_kernel(const ushort* __restrict__ zn,
                                                        float* __restrict__ S,
                                                        float* __restrict__ P) {
  // triangle decode: u = bj*(bj+1)/2 + bi, bi <= bj < 64
  const int u = blockIdx.x;
  int bj = (int)((sqrtf(8.0f * (float)u + 1.0f) - 1.0f) * 0.5f);
  while ((bj + 1) * (bj + 2) / 2 <= u) ++bj;
  while (bj * (bj + 1) / 2 > u) --bj;
  const int bi = u - bj * (bj + 1) / 2;
  const bool diag = (bi == bj);
  const bool posb = (bj == bi + BATCH / 128);

  __shared__ __align__(16) ushort shA[2 * 4096];
  __shared__ __align__(16) ushort shB[2 * 4096];
  __shared__ float redR[2][128];
  __shared__ float redC[2][128];

  const int t    = threadIdx.x;
  const int w    = t >> 6;
  const int l    = t & 63;
  const int quad = l >> 4;
  const int lo   = l & 15;
  const int wm   = w >> 1;
  const int wn   = w & 1;
  const int tileRow = bi * 128;
  const int tileCol = bj * 128;

  // staging: lane l of wave w stages chunks c0 = w*128+l and c1 = c0+64 into
  // LDS at chunk*16B (wave-uniform base + lane*16). Source k-chunk XOR-swizzled.
  const int c0 = w * 128 + l;
  const int c1 = c0 + 64;
  const int r0 = c0 >> 2, k0 = ((c0 & 3) ^ ((r0 >> 1) & 3)) * 8;
  const int r1 = c1 >> 2, k1 = ((c1 & 3) ^ ((r1 >> 1) & 3)) * 8;
  const ushort* gA0 = zn + (size_t)(tileRow + r0) * DIM + k0;
  const ushort* gA1 = zn + (size_t)(tileRow + r1) * DIM + k1;
  const ushort* gB0 = zn + (size_t)(tileCol + r0) * DIM + k0;
  const ushort* gB1 = zn + (size_t)(tileCol + r1) * DIM + k1;
  ushort* lA0 = shA + w * 1024;
  ushort* lA1 = shA + w * 1024 + 512;
  ushort* lB0 = shB + w * 1024;
  ushort* lB1 = shB + w * 1024 + 512;

  floatx4 acc[4][4];
  #pragma unroll
  for (int i = 0; i < 4; ++i)
    #pragma unroll
    for (int j = 0; j < 4; ++j)
      acc[i][j] = (floatx4){0.f, 0.f, 0.f, 0.f};

  // fragment read offsets (ushorts): chunk = R*4 + (quad ^ ((lo>>1)&3))
  const int sw   = (quad ^ ((lo >> 1) & 3)) * 8;
  const int aOff = (wm * 64 + lo) * 32 + sw;  // + i*512
  const int bOff = (wn * 64 + lo) * 32 + sw;  // + j*512

  // prologue: stage K-tile 0 into buffer 0
  ASYNC16(gA0, lA0); ASYNC16(gA1, lA1);
  ASYNC16(gB0, lB0); ASYNC16(gB1, lB1);
  gA0 += 32; gA1 += 32; gB0 += 32; gB1 += 32;

  #pragma unroll
  for (int it = 0; it < 16; ++it) {
    __syncthreads();  // drains loads for buffer `cur` (issued one iter ago)
    const int co = (it & 1) * 4096;
    const int no = co ^ 4096;
    if (it < 15) {
      ASYNC16(gA0, lA0 + no); ASYNC16(gA1, lA1 + no);
      ASYNC16(gB0, lB0 + no); ASYNC16(gB1, lB1 + no);
      gA0 += 32; gA1 += 32; gB0 += 32; gB1 += 32;
    }
    bf16x8 aF[4], bF[4];
    #pragma unroll
    for (int i = 0; i < 4; ++i) aF[i] = *(const bf16x8*)(shA + co + aOff + i * 512);
    #pragma unroll
    for (int j = 0; j < 4; ++j) bF[j] = *(const bf16x8*)(shB + co + bOff + j * 512);
    #pragma unroll
    for (int i = 0; i < 4; ++i)
      #pragma unroll
      for (int j = 0; j < 4; ++j)
        acc[i][j] = __builtin_amdgcn_mfma_f32_16x16x32_bf16(aF[i], bF[j],
                                                            acc[i][j], 0, 0, 0);
  }

  // ---- epilogue. C/D layout: col = lo, row = quad*4 + r (within 16x16)
  float rs[4][4];
  float cs[4];
  #pragma unroll
  for (int i = 0; i < 4; ++i)
    #pragma unroll
    for (int r = 0; r < 4; ++r) rs[i][r] = 0.f;
  #pragma unroll
  for (int j = 0; j < 4; ++j) cs[j] = 0.f;

  #pragma unroll
  for (int i = 0; i < 4; ++i)
    #pragma unroll
    for (int j = 0; j < 4; ++j)
      #pragma unroll
      for (int r = 0; r < 4; ++r) {
        const float e = __expf(acc[i][j][r] * 10.0f - 10.0f);
        rs[i][r] += e;
        cs[j] += e;
      }

  // block-local diagonal lanes: wm==wn, lo == quad*4 + r  (i.e. quad == lo>>2)
  if (wm == wn && quad == (lo >> 2)) {
    const int r = lo & 3;
    if (diag) {  // self-similarity: remove exp from both row and col sums
      #pragma unroll
      for (int i = 0; i < 4; ++i) {
        const float e = __expf(acc[i][i][r] * 10.0f - 10.0f);
        rs[i][r] -= e;
        cs[i] -= e;
      }
    }
    if (posb) {  // positives: col == row + BATCH
      #pragma unroll
      for (int i = 0; i < 4; ++i) {
        const int row = tileRow + wm * 64 + i * 16 + lo;
        const float v = acc[i][i][r] * 10.0f;
        P[row] = v;
        P[row + BATCH] = v;
      }
    }
  }

  // row sums: reduce across the 16 column-lanes (low 4 lane bits)
  #pragma unroll
  for (int m = 1; m < 16; m <<= 1) {
    #pragma unroll
    for (int i = 0; i < 4; ++i)
      #pragma unroll
      for (int r = 0; r < 4; ++r)
        rs[i][r] += __shfl_xor(rs[i][r], m, 64);
  }
  if (lo == 0) {
    #pragma unroll
    for (int i = 0; i < 4; ++i)
      #pragma unroll
      for (int r = 0; r < 4; ++r)
        redR[wn][wm * 64 + i * 16 + quad * 4 + r] = rs[i][r];
  }
  // col sums: reduce across the 4 quads (lane bits 4,5)
  #pragma unroll
  for (int m = 16; m < 64; m <<= 1) {
    #pragma unroll
    for (int j = 0; j < 4; ++j) cs[j] += __shfl_xor(cs[j], m, 64);
  }
  if (quad == 0) {
    #pragma unroll
    for (int j = 0; j < 4; ++j)
      redC[wm][wn * 64 + j * 16 + lo] = cs[j];
  }
  __syncthreads();
  if (t < 128) {
    atomicAdd(&S[tileRow + t], redR[0][t] + redR[1][t]);
  } else if (!diag) {
    const int c = t - 128;
    atomicAdd(&S[tileCol + c], redC[0][c] + redC[1][c]);
  }
  // waves retire here, fire-and-forget on the atomics (no drain — critical).
}

// ---------------------------------------------------------------- final loss
// 32 blocks x 256 threads, 1 element/thread; partial per block, one float
// atomicAdd into out[0] (zeroed by nrm).
__global__ __launch_bounds__(256) void loss_kernel(const float* __restrict__ S,
                                                   const float* __restrict__ P,
                                                   float* __restrict__ out) {
  const int i = blockIdx.x * 256 + threadIdx.x;
  float a = 10.0f + logf(S[i]) - P[i];
  #pragma unroll
  for (int m = 1; m < 64; m <<= 1) a += __shfl_xor(a, m, 64);
  __shared__ float sb[4];
  if ((threadIdx.x & 63) == 0) sb[threadIdx.x >> 6] = a;
  __syncthreads();
  if (threadIdx.x == 0)
    atomicAdd(out, (sb[0] + sb[1] + sb[2] + sb[3]) * (1.0f / (float)NTOT));
}

extern "C" void kernel_launch(void* const* d_in, const int* in_sizes, int n_in,
                              void* d_out, int out_size, void* d_ws, size_t ws_size,
                              hipStream_t stream) {
  const float* zi = (const float*)d_in[0];
  const float* zj = (const float*)d_in[1];
  ushort* zn = (ushort*)d_ws;                                  // 8192*512 bf16 = 8 MB
  float*  S  = (float*)((char*)d_ws + (size_t)NTOT * DIM * 2); // 32 KB
  float*  P  = S + NTOT;                                       // 32 KB
  float*  out = (float*)d_out;

  nrm_kernel<<<NTOT / 4, 256, 0, stream>>>(zi, zj, zn, S, out);
  simsum_kernel<<<NBLK, 256, 0, stream>>>(zn, S, P);
  loss_kernel<<<NTOT / 256, 256, 0, stream>>>(S, P, out);
}

// Round 13
// 101.666 us; speedup vs baseline: 1.2927x; 1.1738x over previous
//
#include <hip/hip_runtime.h>
#include <hip/hip_bf16.h>

#define BATCH 4096
#define NTOT  8192
#define DIM   512
#define NBLK  2080

typedef __attribute__((ext_vector_type(4))) float floatx4;

#define ASYNC16(gp, lp)                                                        \
  __builtin_amdgcn_global_load_lds(                                            \
      (__attribute__((address_space(1))) void*)(gp),                           \
      (__attribute__((address_space(3))) void*)(lp), 16, 0, 0)

// ---------------------------------------------------------------- normalize
// One wave per row: read 512 fp32, rsqrt(sum sq), write 512 fp8 e4m3 scaled
// by 16 (pushes |z|~0.04 into e4m3's normal range; epilogue divides by 256).
// Blocks 0..31 also zero S; block 32 zeroes out[0].
__global__ __launch_bounds__(256) void nrm_kernel(const float* __restrict__ zi,
                                                  const float* __restrict__ zj,
                                                  unsigned char* __restrict__ zn,
                                                  float* __restrict__ S,
                                                  float* __restrict__ out) {
  if (blockIdx.x < 32) S[blockIdx.x * 256 + threadIdx.x] = 0.0f;
  if (blockIdx.x == 32 && threadIdx.x == 0) out[0] = 0.0f;
  const int row = blockIdx.x * 4 + (threadIdx.x >> 6);
  const int l   = threadIdx.x & 63;
  const float* src = (row < BATCH) ? (zi + (size_t)row * DIM)
                                   : (zj + (size_t)(row - BATCH) * DIM);
  const float4* s4 = (const float4*)src;
  float4 v0 = s4[l];
  float4 v1 = s4[l + 64];
  float ss = v0.x*v0.x + v0.y*v0.y + v0.z*v0.z + v0.w*v0.w
           + v1.x*v1.x + v1.y*v1.y + v1.z*v1.z + v1.w*v1.w;
  #pragma unroll
  for (int m = 1; m < 64; m <<= 1) ss += __shfl_xor(ss, m, 64);
  const float r = 16.0f / fmaxf(sqrtf(ss), 1e-12f);   // x16 prescale
  int p0 = __builtin_amdgcn_cvt_pk_fp8_f32(v0.x * r, v0.y * r, 0, false);
  p0     = __builtin_amdgcn_cvt_pk_fp8_f32(v0.z * r, v0.w * r, p0, true);
  int p1 = __builtin_amdgcn_cvt_pk_fp8_f32(v1.x * r, v1.y * r, 0, false);
  p1     = __builtin_amdgcn_cvt_pk_fp8_f32(v1.z * r, v1.w * r, p1, true);
  int* d = (int*)(zn + (size_t)row * DIM);
  d[l]       = p0;     // bytes 4l..4l+3   = k 4l..4l+3
  d[l + 64]  = p1;     // bytes 256+4l..   = k 256+4l..
}

// ---------------------------------------------------------------- main GEMM
// Champion R5 shell (128x128 tile, 4 waves, 2-buffer LDS, one __syncthreads
// per K-iter, compiler-scheduled) ported to FP8 e4m3, BK=64 (8 iters).
// WHY fp8 (R12 post-mortem): LDS pipe is the largest per-iter consumer
// (~512 of 1025 CU-cycles: 384 read + 128 staging-write) and staging traffic
// (532MB L2-side / 81MB HBM) drives the latency that 2-wave/SIMD occupancy
// can't hide. fp8 halves LDS reads, LDS writes, L2 and HBM bytes at IDENTICAL
// MFMA cycles (non-scaled fp8 16x16x32 = bf16 rate). BK=64 keeps LDS/iter at
// 16KB -> same 35KB footprint & occupancy as champion (unlike R7's bf16 BK=64).
// LDS layout per matrix/buffer: 128 rows x 8 slots x 8B; slot s of row r holds
// k8-chunk kc = s ^ (r&6). Staging 16B chunks {2m,2m+1} source contiguous
// k-bytes at (2m^(r&6))*8 (x even -> contiguity holds); fragment ds_read_b64
// at slot (kk*4+quad)^(lo&6) cancels the store XOR (identity k-map, A/B agree)
// and is only 2-way bank-aliased (free, m136).
// Lessons pinned: (256,3) hint regression (R12). rep-loop regression (R11).
// 256² tile regression (R10). Rule #20: no runtime array index into acc
// (R8/R9). BK=64-bf16 regression (R7). depth-2 prefetch null (R6). NO fused
// loss tail (+15us R3/R4). NO agent ACQ_REL (+25us R1/R2). NO XCD swizzle.
// NO sched_barrier pinning (R1/m141).
__global__ __launch_bounds__(256) void simsum_kernel(const unsigned char* __restrict__ zn,
                                                     float* __restrict__ S,
                                                     float* __restrict__ P) {
  // triangle decode: u = bj*(bj+1)/2 + bi, bi <= bj < 64
  const int u = blockIdx.x;
  int bj = (int)((sqrtf(8.0f * (float)u + 1.0f) - 1.0f) * 0.5f);
  while ((bj + 1) * (bj + 2) / 2 <= u) ++bj;
  while (bj * (bj + 1) / 2 > u) --bj;
  const int bi = u - bj * (bj + 1) / 2;
  const bool diag = (bi == bj);
  const bool posb = (bj == bi + BATCH / 128);

  __shared__ __align__(16) unsigned char shA[2 * 8192];  // 2 buf x 128 x 64B
  __shared__ __align__(16) unsigned char shB[2 * 8192];
  __shared__ float redR[2][128];
  __shared__ float redC[2][128];

  const int t    = threadIdx.x;
  const int w    = t >> 6;
  const int l    = t & 63;
  const int quad = l >> 4;
  const int lo   = l & 15;
  const int wm   = w >> 1;
  const int wn   = w & 1;
  const int tileRow = bi * 128;
  const int tileCol = bj * 128;

  // staging: thread t stages chunks c0 = t and c1 = t + 256 per matrix.
  // chunk c: row r = c>>2, m = c&3; 16B covers slots {2m,2m+1} = source
  // k-bytes (2m ^ (r&6))*8 .. +16 of row r's current K-segment.
  const int c0 = t;               // = w*64 + l (wave-uniform base + lane*16)
  const int r0 = c0 >> 2, m0 = c0 & 3;
  const int off0 = ((2 * m0) ^ (r0 & 6)) * 8;   // same for r0+64 (64&6==0)
  const unsigned char* gA0 = zn + (size_t)(tileRow + r0) * DIM + off0;
  const unsigned char* gA1 = zn + (size_t)(tileRow + r0 + 64) * DIM + off0;
  const unsigned char* gB0 = zn + (size_t)(tileCol + r0) * DIM + off0;
  const unsigned char* gB1 = zn + (size_t)(tileCol + r0 + 64) * DIM + off0;
  unsigned char* lA0 = shA + w * 1024;           // chunk c0*16, lane adds l*16
  unsigned char* lA1 = shA + w * 1024 + 4096;    // chunk c1*16
  unsigned char* lB0 = shB + w * 1024;
  unsigned char* lB1 = shB + w * 1024 + 4096;

  floatx4 acc[4][4];
  #pragma unroll
  for (int i = 0; i < 4; ++i)
    #pragma unroll
    for (int j = 0; j < 4; ++j)
      acc[i][j] = (floatx4){0.f, 0.f, 0.f, 0.f};

  // fragment reads: row = (wm|wn)*64 + i*16 + lo, row stride 64B;
  // slot for kk = (kk*4+quad) ^ (lo&6)  (row&6 == lo&6 since 16|64 ≡ 0 mod 8)
  const int s0 = ((quad ^ (lo & 6))) * 8;   // kk=0 slot byte offset
  const int s1 = s0 ^ 32;                   // kk=1 (xor with 4<<3)
  const int aRow = (wm * 64 + lo) * 64;     // + i*1024
  const int bRow = (wn * 64 + lo) * 64;     // + j*1024

  // prologue: stage K-tile 0 into buffer 0
  ASYNC16(gA0, lA0); ASYNC16(gA1, lA1);
  ASYNC16(gB0, lB0); ASYNC16(gB1, lB1);
  gA0 += 64; gA1 += 64; gB0 += 64; gB1 += 64;

  #pragma unroll
  for (int it = 0; it < 8; ++it) {
    __syncthreads();  // drains loads for buffer `cur` (issued one iter ago)
    const int co = (it & 1) * 8192;
    const int no = co ^ 8192;
    if (it < 7) {
      ASYNC16(gA0, lA0 + no); ASYNC16(gA1, lA1 + no);
      ASYNC16(gB0, lB0 + no); ASYNC16(gB1, lB1 + no);
      gA0 += 64; gA1 += 64; gB0 += 64; gB1 += 64;
    }
    long a0[4], a1[4], b0[4], b1[4];
    #pragma unroll
    for (int i = 0; i < 4; ++i) {
      a0[i] = *(const long*)(shA + co + aRow + i * 1024 + s0);
      a1[i] = *(const long*)(shA + co + aRow + i * 1024 + s1);
    }
    #pragma unroll
    for (int j = 0; j < 4; ++j) {
      b0[j] = *(const long*)(shB + co + bRow + j * 1024 + s0);
      b1[j] = *(const long*)(shB + co + bRow + j * 1024 + s1);
    }
    #pragma unroll
    for (int i = 0; i < 4; ++i)
      #pragma unroll
      for (int j = 0; j < 4; ++j) {
        acc[i][j] = __builtin_amdgcn_mfma_f32_16x16x32_fp8_fp8(a0[i], b0[j],
                                                               acc[i][j], 0, 0, 0);
        acc[i][j] = __builtin_amdgcn_mfma_f32_16x16x32_fp8_fp8(a1[i], b1[j],
                                                               acc[i][j], 0, 0, 0);
      }
  }

  // ---- epilogue. C/D layout: col = lo, row = quad*4 + r (within 16x16).
  // acc holds 256*sim (x16 prescale on both operands) -> logit = acc*10/256.
  const float LS = 10.0f / 256.0f;
  float rs[4][4];
  float cs[4];
  #pragma unroll
  for (int i = 0; i < 4; ++i)
    #pragma unroll
    for (int r = 0; r < 4; ++r) rs[i][r] = 0.f;
  #pragma unroll
  for (int j = 0; j < 4; ++j) cs[j] = 0.f;

  #pragma unroll
  for (int i = 0; i < 4; ++i)
    #pragma unroll
    for (int j = 0; j < 4; ++j)
      #pragma unroll
      for (int r = 0; r < 4; ++r) {
        const float e = __expf(acc[i][j][r] * LS - 10.0f);
        rs[i][r] += e;
        cs[j] += e;
      }

  // block-local diagonal lanes: wm==wn, lo == quad*4 + r  (i.e. quad == lo>>2)
  if (wm == wn && quad == (lo >> 2)) {
    const int r = lo & 3;
    if (diag) {  // self-similarity: remove exp from both row and col sums
      #pragma unroll
      for (int i = 0; i < 4; ++i) {
        const float e = __expf(acc[i][i][r] * LS - 10.0f);
        rs[i][r] -= e;
        cs[i] -= e;
      }
    }
    if (posb) {  // positives: col == row + BATCH
      #pragma unroll
      for (int i = 0; i < 4; ++i) {
        const int row = tileRow + wm * 64 + i * 16 + lo;
        const float v = acc[i][i][r] * LS;
        P[row] = v;
        P[row + BATCH] = v;
      }
    }
  }

  // row sums: reduce across the 16 column-lanes (low 4 lane bits)
  #pragma unroll
  for (int m = 1; m < 16; m <<= 1) {
    #pragma unroll
    for (int i = 0; i < 4; ++i)
      #pragma unroll
      for (int r = 0; r < 4; ++r)
        rs[i][r] += __shfl_xor(rs[i][r], m, 64);
  }
  if (lo == 0) {
    #pragma unroll
    for (int i = 0; i < 4; ++i)
      #pragma unroll
      for (int r = 0; r < 4; ++r)
        redR[wn][wm * 64 + i * 16 + quad * 4 + r] = rs[i][r];
  }
  // col sums: reduce across the 4 quads (lane bits 4,5)
  #pragma unroll
  for (int m = 16; m < 64; m <<= 1) {
    #pragma unroll
    for (int j = 0; j < 4; ++j) cs[j] += __shfl_xor(cs[j], m, 64);
  }
  if (quad == 0) {
    #pragma unroll
    for (int j = 0; j < 4; ++j)
      redC[wm][wn * 64 + j * 16 + lo] = cs[j];
  }
  __syncthreads();
  if (t < 128) {
    atomicAdd(&S[tileRow + t], redR[0][t] + redR[1][t]);
  } else if (!diag) {
    const int c = t - 128;
    atomicAdd(&S[tileCol + c], redC[0][c] + redC[1][c]);
  }
  // waves retire here, fire-and-forget on the atomics (no drain — critical).
}

// ---------------------------------------------------------------- final loss
// 32 blocks x 256 threads, 1 element/thread; partial per block, one float
// atomicAdd into out[0] (zeroed by nrm).
__global__ __launch_bounds__(256) void loss_kernel(const float* __restrict__ S,
                                                   const float* __restrict__ P,
                                                   float* __restrict__ out) {
  const int i = blockIdx.x * 256 + threadIdx.x;
  float a = 10.0f + logf(S[i]) - P[i];
  #pragma unroll
  for (int m = 1; m < 64; m <<= 1) a += __shfl_xor(a, m, 64);
  __shared__ float sb[4];
  if ((threadIdx.x & 63) == 0) sb[threadIdx.x >> 6] = a;
  __syncthreads();
  if (threadIdx.x == 0)
    atomicAdd(out, (sb[0] + sb[1] + sb[2] + sb[3]) * (1.0f / (float)NTOT));
}

extern "C" void kernel_launch(void* const* d_in, const int* in_sizes, int n_in,
                              void* d_out, int out_size, void* d_ws, size_t ws_size,
                              hipStream_t stream) {
  const float* zi = (const float*)d_in[0];
  const float* zj = (const float*)d_in[1];
  unsigned char* zn = (unsigned char*)d_ws;                    // 8192*512 fp8 = 4 MB
  float*  S  = (float*)((char*)d_ws + (size_t)NTOT * DIM * 2); // (offset kept)
  float*  P  = S + NTOT;                                       // 32 KB
  float*  out = (float*)d_out;

  nrm_kernel<<<NTOT / 4, 256, 0, stream>>>(zi, zj, zn, S, out);
  simsum_kernel<<<NBLK, 256, 0, stream>>>(zn, S, P);
  loss_kernel<<<NTOT / 256, 256, 0, stream>>>(S, P, out);
}

// Round 14
// 98.805 us; speedup vs baseline: 1.3301x; 1.0290x over previous
//
#include <hip/hip_runtime.h>
#include <hip/hip_bf16.h>

#define BATCH 4096
#define NTOT  8192
#define DIM   512
#define NBLK  2080

typedef __attribute__((ext_vector_type(4))) float floatx4;
typedef __attribute__((ext_vector_type(8))) int   intx8;

#define ASYNC16(gp, lp)                                                        \
  __builtin_amdgcn_global_load_lds(                                            \
      (__attribute__((address_space(1))) void*)(gp),                           \
      (__attribute__((address_space(3))) void*)(lp), 16, 0, 0)

// ---------------------------------------------------------------- normalize
// One wave per row: read 512 fp32, rsqrt(sum sq), write 512 fp8 e4m3 scaled
// by 16 (epilogue divides by 256). Blocks 0..31 zero S; block 32 zeroes out.
__global__ __launch_bounds__(256) void nrm_kernel(const float* __restrict__ zi,
                                                  const float* __restrict__ zj,
                                                  unsigned char* __restrict__ zn,
                                                  float* __restrict__ S,
                                                  float* __restrict__ out) {
  if (blockIdx.x < 32) S[blockIdx.x * 256 + threadIdx.x] = 0.0f;
  if (blockIdx.x == 32 && threadIdx.x == 0) out[0] = 0.0f;
  const int row = blockIdx.x * 4 + (threadIdx.x >> 6);
  const int l   = threadIdx.x & 63;
  const float* src = (row < BATCH) ? (zi + (size_t)row * DIM)
                                   : (zj + (size_t)(row - BATCH) * DIM);
  const float4* s4 = (const float4*)src;
  float4 v0 = s4[l];
  float4 v1 = s4[l + 64];
  float ss = v0.x*v0.x + v0.y*v0.y + v0.z*v0.z + v0.w*v0.w
           + v1.x*v1.x + v1.y*v1.y + v1.z*v1.z + v1.w*v1.w;
  #pragma unroll
  for (int m = 1; m < 64; m <<= 1) ss += __shfl_xor(ss, m, 64);
  const float r = 16.0f / fmaxf(sqrtf(ss), 1e-12f);   // x16 prescale
  int p0 = __builtin_amdgcn_cvt_pk_fp8_f32(v0.x * r, v0.y * r, 0, false);
  p0     = __builtin_amdgcn_cvt_pk_fp8_f32(v0.z * r, v0.w * r, p0, true);
  int p1 = __builtin_amdgcn_cvt_pk_fp8_f32(v1.x * r, v1.y * r, 0, false);
  p1     = __builtin_amdgcn_cvt_pk_fp8_f32(v1.z * r, v1.w * r, p1, true);
  int* d = (int*)(zn + (size_t)row * DIM);
  d[l]       = p0;
  d[l + 64]  = p1;
}

// ---------------------------------------------------------------- main GEMM
// R13 champion shell (128x128 tile, 4 waves, 2-buffer LDS, one __syncthreads
// per K-iter) upgraded to MX-scaled FP8: mfma_scale_f32_16x16x128_f8f6f4 with
// scales pinned to 1.0 (E8M0 byte 127) -> numerically identical to R13's
// fp8 math but 2x the MFMA rate (4661 vs 2047 TF ubench). MFMA was the
// largest remaining pipe (~13us of ~40us). BK=128 -> 4 K-iters.
// 16x16x128 chosen over 32x32x64 because its C/D layout is IDENTICAL to the
// verified 16x16x32 mapping (shape-determined, m121-128) -> epilogue is
// byte-identical to R13's passing code.
// Operand layout: lane holds row l&15, k-bytes (l>>4)*32..+32 (contiguous
// 32B), read as 2x ds_read_b128 from slot-swizzled LDS.
// LDS per matrix/buffer: 128 rows x 8 slots x 16B; slot s of row r holds
// k-chunk s^(r&7) (inverse XOR on global source; dest linear). Fragment
// reads land on slots (2q)^(lo&7),(2q+1)^(lo&7): rows 0-7 cover all 32
// banks, rows 8-15 alias 2-way = free (m136).
// Lessons pinned: fp8 e2e win (R13). (256,3) hint regression (R12). rep-loop
// regression (R11). 256² tile regression (R10). Rule #20: no runtime array
// index into acc (R8/R9). BK=64-bf16 regression (R7). depth-2 null (R6).
// NO fused loss tail (R3/R4). NO agent ACQ_REL (R1/R2). NO XCD swizzle.
// NO sched_barrier pinning (R1/m141).
__global__ __launch_bounds__(256) void simsum_kernel(const unsigned char* __restrict__ zn,
                                                     float* __restrict__ S,
                                                     float* __restrict__ P) {
  // triangle decode: u = bj*(bj+1)/2 + bi, bi <= bj < 64
  const int u = blockIdx.x;
  int bj = (int)((sqrtf(8.0f * (float)u + 1.0f) - 1.0f) * 0.5f);
  while ((bj + 1) * (bj + 2) / 2 <= u) ++bj;
  while (bj * (bj + 1) / 2 > u) --bj;
  const int bi = u - bj * (bj + 1) / 2;
  const bool diag = (bi == bj);
  const bool posb = (bj == bi + BATCH / 128);

  __shared__ __align__(16) unsigned char shA[2 * 16384];  // 2 buf x 128 x 128B
  __shared__ __align__(16) unsigned char shB[2 * 16384];
  __shared__ float redR[2][128];
  __shared__ float redC[2][128];

  const int t    = threadIdx.x;
  const int w    = t >> 6;
  const int l    = t & 63;
  const int quad = l >> 4;
  const int lo   = l & 15;
  const int wm   = w >> 1;
  const int wn   = w & 1;
  const int tileRow = bi * 128;
  const int tileCol = bj * 128;

  // staging: thread t stages chunks {t, t+256, t+512, t+768} per matrix.
  // chunk p: row r = p>>3 = (t>>3)+32m, slot s = p&7 = t&7 (256m: +32 rows,
  // slot unchanged). Content k-chunk = s ^ (r&7) = (t&7) ^ ((t>>3)&7):
  // CONSTANT per thread. Dest = chunk*16 (linear; wave-uniform base + l*16).
  const int rr   = t >> 3;                      // row of chunk m=0
  const int koff = ((t & 7) ^ (rr & 7)) * 16;   // same for all m
  const unsigned char* gA0 = zn + (size_t)(tileRow + rr      ) * DIM + koff;
  const unsigned char* gA1 = zn + (size_t)(tileRow + rr + 32 ) * DIM + koff;
  const unsigned char* gA2 = zn + (size_t)(tileRow + rr + 64 ) * DIM + koff;
  const unsigned char* gA3 = zn + (size_t)(tileRow + rr + 96 ) * DIM + koff;
  const unsigned char* gB0 = zn + (size_t)(tileCol + rr      ) * DIM + koff;
  const unsigned char* gB1 = zn + (size_t)(tileCol + rr + 32 ) * DIM + koff;
  const unsigned char* gB2 = zn + (size_t)(tileCol + rr + 64 ) * DIM + koff;
  const unsigned char* gB3 = zn + (size_t)(tileCol + rr + 96 ) * DIM + koff;
  unsigned char* lA = shA + w * 1024;           // + m*4096 (+bufo); HW adds l*16
  unsigned char* lB = shB + w * 1024;

  floatx4 acc[4][4];
  #pragma unroll
  for (int i = 0; i < 4; ++i)
    #pragma unroll
    for (int j = 0; j < 4; ++j)
      acc[i][j] = (floatx4){0.f, 0.f, 0.f, 0.f};

  // fragment reads: row = (wm|wn)*64 + i*16 + lo, row stride 128B;
  // quad q needs k-chunks {2q, 2q+1} at slots ({2q,2q+1})^(lo&7).
  const int s0   = ((2 * quad)     ^ (lo & 7)) * 16;
  const int s1   = ((2 * quad + 1) ^ (lo & 7)) * 16;
  const int aRow = (wm * 64 + lo) * 128;   // + i*2048
  const int bRow = (wn * 64 + lo) * 128;   // + j*2048

  #define STAGE(bufo)                                                         \
    ASYNC16(gA0, lA + (bufo));          ASYNC16(gA1, lA + (bufo) + 4096);     \
    ASYNC16(gA2, lA + (bufo) + 8192);   ASYNC16(gA3, lA + (bufo) + 12288);    \
    ASYNC16(gB0, lB + (bufo));          ASYNC16(gB1, lB + (bufo) + 4096);     \
    ASYNC16(gB2, lB + (bufo) + 8192);   ASYNC16(gB3, lB + (bufo) + 12288);    \
    gA0 += 128; gA1 += 128; gA2 += 128; gA3 += 128;                           \
    gB0 += 128; gB1 += 128; gB2 += 128; gB3 += 128;

  // prologue: stage K-tile 0 into buffer 0
  STAGE(0)

  #pragma unroll
  for (int it = 0; it < 4; ++it) {
    __syncthreads();  // drains loads for buffer `cur` (issued one iter ago)
    const int co = (it & 1) * 16384;
    const int no = co ^ 16384;
    if (it < 3) { STAGE(no) }
    union frag { int4 h[2]; intx8 v; };
    frag aF[4], bF[4];
    #pragma unroll
    for (int i = 0; i < 4; ++i) {
      aF[i].h[0] = *(const int4*)(shA + co + aRow + i * 2048 + s0);
      aF[i].h[1] = *(const int4*)(shA + co + aRow + i * 2048 + s1);
    }
    #pragma unroll
    for (int j = 0; j < 4; ++j) {
      bF[j].h[0] = *(const int4*)(shB + co + bRow + j * 2048 + s0);
      bF[j].h[1] = *(const int4*)(shB + co + bRow + j * 2048 + s1);
    }
    #pragma unroll
    for (int i = 0; i < 4; ++i)
      #pragma unroll
      for (int j = 0; j < 4; ++j)
        // fmt 0/0 = fp8 e4m3 both; scales = E8M0 127 = 1.0 (opsel byte 0)
        acc[i][j] = __builtin_amdgcn_mfma_scale_f32_16x16x128_f8f6f4(
            aF[i].v, bF[j].v, acc[i][j], 0, 0, 0, 127, 0, 127);
  }
  #undef STAGE

  // ---- epilogue (byte-identical to R13). C/D: col = lo, row = quad*4 + r.
  // acc holds 256*sim -> logit = acc*10/256.
  const float LS = 10.0f / 256.0f;
  float rs[4][4];
  float cs[4];
  #pragma unroll
  for (int i = 0; i < 4; ++i)
    #pragma unroll
    for (int r = 0; r < 4; ++r) rs[i][r] = 0.f;
  #pragma unroll
  for (int j = 0; j < 4; ++j) cs[j] = 0.f;

  #pragma unroll
  for (int i = 0; i < 4; ++i)
    #pragma unroll
    for (int j = 0; j < 4; ++j)
      #pragma unroll
      for (int r = 0; r < 4; ++r) {
        const float e = __expf(acc[i][j][r] * LS - 10.0f);
        rs[i][r] += e;
        cs[j] += e;
      }

  // block-local diagonal lanes: wm==wn, lo == quad*4 + r  (i.e. quad == lo>>2)
  if (wm == wn && quad == (lo >> 2)) {
    const int r = lo & 3;
    if (diag) {  // self-similarity: remove exp from both row and col sums
      #pragma unroll
      for (int i = 0; i < 4; ++i) {
        const float e = __expf(acc[i][i][r] * LS - 10.0f);
        rs[i][r] -= e;
        cs[i] -= e;
      }
    }
    if (posb) {  // positives: col == row + BATCH
      #pragma unroll
      for (int i = 0; i < 4; ++i) {
        const int row = tileRow + wm * 64 + i * 16 + lo;
        const float v = acc[i][i][r] * LS;
        P[row] = v;
        P[row + BATCH] = v;
      }
    }
  }

  // row sums: reduce across the 16 column-lanes (low 4 lane bits)
  #pragma unroll
  for (int m = 1; m < 16; m <<= 1) {
    #pragma unroll
    for (int i = 0; i < 4; ++i)
      #pragma unroll
      for (int r = 0; r < 4; ++r)
        rs[i][r] += __shfl_xor(rs[i][r], m, 64);
  }
  if (lo == 0) {
    #pragma unroll
    for (int i = 0; i < 4; ++i)
      #pragma unroll
      for (int r = 0; r < 4; ++r)
        redR[wn][wm * 64 + i * 16 + quad * 4 + r] = rs[i][r];
  }
  // col sums: reduce across the 4 quads (lane bits 4,5)
  #pragma unroll
  for (int m = 16; m < 64; m <<= 1) {
    #pragma unroll
    for (int j = 0; j < 4; ++j) cs[j] += __shfl_xor(cs[j], m, 64);
  }
  if (quad == 0) {
    #pragma unroll
    for (int j = 0; j < 4; ++j)
      redC[wm][wn * 64 + j * 16 + lo] = cs[j];
  }
  __syncthreads();
  if (t < 128) {
    atomicAdd(&S[tileRow + t], redR[0][t] + redR[1][t]);
  } else if (!diag) {
    const int c = t - 128;
    atomicAdd(&S[tileCol + c], redC[0][c] + redC[1][c]);
  }
  // waves retire here, fire-and-forget on the atomics (no drain — critical).
}

// ---------------------------------------------------------------- final loss
// 32 blocks x 256 threads, 1 element/thread; partial per block, one float
// atomicAdd into out[0] (zeroed by nrm).
__global__ __launch_bounds__(256) void loss_kernel(const float* __restrict__ S,
                                                   const float* __restrict__ P,
                                                   float* __restrict__ out) {
  const int i = blockIdx.x * 256 + threadIdx.x;
  float a = 10.0f + logf(S[i]) - P[i];
  #pragma unroll
  for (int m = 1; m < 64; m <<= 1) a += __shfl_xor(a, m, 64);
  __shared__ float sb[4];
  if ((threadIdx.x & 63) == 0) sb[threadIdx.x >> 6] = a;
  __syncthreads();
  if (threadIdx.x == 0)
    atomicAdd(out, (sb[0] + sb[1] + sb[2] + sb[3]) * (1.0f / (float)NTOT));
}

extern "C" void kernel_launch(void* const* d_in, const int* in_sizes, int n_in,
                              void* d_out, int out_size, void* d_ws, size_t ws_size,
                              hipStream_t stream) {
  const float* zi = (const float*)d_in[0];
  const float* zj = (const float*)d_in[1];
  unsigned char* zn = (unsigned char*)d_ws;                    // 8192*512 fp8 = 4 MB
  float*  S  = (float*)((char*)d_ws + (size_t)NTOT * DIM * 2); // (offset kept)
  float*  P  = S + NTOT;                                       // 32 KB
  float*  out = (float*)d_out;

  nrm_kernel<<<NTOT / 4, 256, 0, stream>>>(zi, zj, zn, S, out);
  simsum_kernel<<<NBLK, 256, 0, stream>>>(zn, S, P);
  loss_kernel<<<NTOT / 256, 256, 0, stream>>>(S, P, out);
}

// Round 15
// 89.530 us; speedup vs baseline: 1.4679x; 1.1036x over previous
//
#include <hip/hip_runtime.h>
#include <hip/hip_bf16.h>

#define BATCH 4096
#define NTOT  8192
#define DIM   512
#define NBLK  2080

typedef __attribute__((ext_vector_type(4))) float floatx4;
typedef __attribute__((ext_vector_type(8))) int   intx8;

#define ASYNC16(gp, lp)                                                        \
  __builtin_amdgcn_global_load_lds(                                            \
      (__attribute__((address_space(1))) void*)(gp),                           \
      (__attribute__((address_space(3))) void*)(lp), 16, 0, 0)

// e2m1 (OCP MXFP4) RNE quantizer for scaled value v; returns 4-bit code.
// Grid {0, 0.5, 1, 1.5, 2, 3, 4, 6}; code = index, sign in bit 3.
__device__ __forceinline__ unsigned q4(float v) {
  const float m = fabsf(v);
  int c;
  if      (m < 0.25f) c = 0;
  else if (m < 0.75f) c = 1;
  else if (m < 1.25f) c = 2;
  else if (m < 1.75f) c = 3;
  else if (m < 2.50f) c = 4;
  else if (m < 3.50f) c = 5;
  else if (m < 5.00f) c = 6;
  else                c = 7;
  return (unsigned)(c | (v < 0.0f ? 8 : 0));
}

// ---------------------------------------------------------------- normalize
// One wave per row: read 512 fp32, rsqrt(sum sq), write 512 fp4 e2m1 scaled
// by 64 (sigma_scaled ~2.8, clip at 6 = 2.1 sigma; epilogue divides by 4096).
// Error analysis (R15): per-coord RNE noise sigma~0.005 normalized ->
// sim noise 0.007 -> loss bias ~2.5e-3. Blocks 0..31 zero S; block 32 zeroes out.
__global__ __launch_bounds__(256) void nrm_kernel(const float* __restrict__ zi,
                                                  const float* __restrict__ zj,
                                                  unsigned char* __restrict__ zn,
                                                  float* __restrict__ S,
                                                  float* __restrict__ out) {
  if (blockIdx.x < 32) S[blockIdx.x * 256 + threadIdx.x] = 0.0f;
  if (blockIdx.x == 32 && threadIdx.x == 0) out[0] = 0.0f;
  const int row = blockIdx.x * 4 + (threadIdx.x >> 6);
  const int l   = threadIdx.x & 63;
  const float* src = (row < BATCH) ? (zi + (size_t)row * DIM)
                                   : (zj + (size_t)(row - BATCH) * DIM);
  const float4* s4 = (const float4*)src;
  float4 v0 = s4[l];
  float4 v1 = s4[l + 64];
  float ss = v0.x*v0.x + v0.y*v0.y + v0.z*v0.z + v0.w*v0.w
           + v1.x*v1.x + v1.y*v1.y + v1.z*v1.z + v1.w*v1.w;
  #pragma unroll
  for (int m = 1; m < 64; m <<= 1) ss += __shfl_xor(ss, m, 64);
  const float r = 64.0f / fmaxf(sqrtf(ss), 1e-12f);   // x64 prescale
  // pack 4 values -> 2 bytes (2 nibbles/byte, low nibble = even k)
  unsigned short p0 = (unsigned short)(q4(v0.x * r) | (q4(v0.y * r) << 4)
                     | (q4(v0.z * r) << 8) | (q4(v0.w * r) << 12));
  unsigned short p1 = (unsigned short)(q4(v1.x * r) | (q4(v1.y * r) << 4)
                     | (q4(v1.z * r) << 8) | (q4(v1.w * r) << 12));
  unsigned short* d = (unsigned short*)(zn + (size_t)row * 256);
  d[l]      = p0;    // k 4l..4l+3
  d[l + 64] = p1;    // k 256+4l..+3
}

// ---------------------------------------------------------------- main GEMM
// R14 champion shell (128x128 tile, 4 waves, 2-buffer LDS, one __syncthreads
// per K-iter, BK=128, mfma_scale 16x16x128) with operands in MX-FP4 (e2m1),
// scales pinned 1.0 (E8M0 127), cbsz=blgp=4. vs R14: MFMA rate 2x (fp4 MX
// ~9 PF ubench), ALL byte streams halve (rows 256B; fragment = 16B/lane =
// ONE ds_read_b128; LDS back to 35KB champion footprint).
// Numerical safety: any consistent k-permutation/nibble-order cancels in
// A.B (both operands from the same packed zn); only the e2m1 decode grid
// {0,.5,1,1.5,2,3,4,6} matters. acc = 4096*sim -> LS = 10/4096.
// LDS layout per matrix/buffer: 128 rows x 4 slots x 16B; slot s of row r
// holds k-chunk s ^ (r&3) ^ ((r>>2)&3) (involution; inverse XOR applied on
// global source, dest linear). Fragment read slot = quad ^ (lo&3) ^
// ((lo>>2)&3): lanes {lo,lo+4,lo+8,lo+12} hit distinct 16B windows ->
// conflict-free b128.
// Lessons pinned: MX-fp8 win (R14), fp8 win (R13). (256,3) hint regression
// (R12). rep-loop regression (R11). 256² regression (R10). Rule #20 (R8/R9).
// BK=64-bf16 regression (R7). depth-2 null (R6). NO fused loss tail (R3/R4).
// NO agent ACQ_REL (R1/R2). NO XCD swizzle. NO sched_barrier pinning (R1).
__global__ __launch_bounds__(256) void simsum_kernel(const unsigned char* __restrict__ zn,
                                                     float* __restrict__ S,
                                                     float* __restrict__ P) {
  // triangle decode: u = bj*(bj+1)/2 + bi, bi <= bj < 64
  const int u = blockIdx.x;
  int bj = (int)((sqrtf(8.0f * (float)u + 1.0f) - 1.0f) * 0.5f);
  while ((bj + 1) * (bj + 2) / 2 <= u) ++bj;
  while (bj * (bj + 1) / 2 > u) --bj;
  const int bi = u - bj * (bj + 1) / 2;
  const bool diag = (bi == bj);
  const bool posb = (bj == bi + BATCH / 128);

  __shared__ __align__(16) unsigned char shA[2 * 8192];  // 2 buf x 128 x 64B
  __shared__ __align__(16) unsigned char shB[2 * 8192];
  __shared__ float redR[2][128];
  __shared__ float redC[2][128];

  const int t    = threadIdx.x;
  const int w    = t >> 6;
  const int l    = t & 63;
  const int quad = l >> 4;
  const int lo   = l & 15;
  const int wm   = w >> 1;
  const int wn   = w & 1;
  const int tileRow = bi * 128;
  const int tileCol = bj * 128;

  // staging: thread t stages chunks {t, t+256} per matrix (512 chunks =
  // 128 rows x 4 slots x 16B per K-tile). chunk c: row r = c>>2, slot s=c&3;
  // content k-chunk = s ^ (r&3) ^ ((r>>2)&3). Second chunk: +64 rows, same
  // slot -> same XOR (64 = 0 mod 4 in both terms) -> koff constant/thread.
  const int rr   = t >> 2;                                    // 0..63
  const int koff = ((t & 3) ^ (rr & 3) ^ ((rr >> 2) & 3)) * 16;
  const unsigned char* gA0 = zn + (size_t)(tileRow + rr     ) * 256 + koff;
  const unsigned char* gA1 = zn + (size_t)(tileRow + rr + 64) * 256 + koff;
  const unsigned char* gB0 = zn + (size_t)(tileCol + rr     ) * 256 + koff;
  const unsigned char* gB1 = zn + (size_t)(tileCol + rr + 64) * 256 + koff;
  unsigned char* lA0 = shA + w * 1024;          // chunk t*16 (HW adds l*16)
  unsigned char* lA1 = shA + w * 1024 + 4096;   // chunk (t+256)*16
  unsigned char* lB0 = shB + w * 1024;
  unsigned char* lB1 = shB + w * 1024 + 4096;

  floatx4 acc[4][4];
  #pragma unroll
  for (int i = 0; i < 4; ++i)
    #pragma unroll
    for (int j = 0; j < 4; ++j)
      acc[i][j] = (floatx4){0.f, 0.f, 0.f, 0.f};

  // fragment reads: row = (wm|wn)*64 + i*16 + lo, row stride 64B;
  // quad needs k-chunk `quad` at slot quad ^ (lo&3) ^ ((lo>>2)&3).
  const int sw   = (quad ^ (lo & 3) ^ ((lo >> 2) & 3)) * 16;
  const int aRow = (wm * 64 + lo) * 64 + sw;   // + i*1024
  const int bRow = (wn * 64 + lo) * 64 + sw;   // + j*1024

  #define STAGE(bufo)                                                         \
    ASYNC16(gA0, lA0 + (bufo)); ASYNC16(gA1, lA1 + (bufo));                   \
    ASYNC16(gB0, lB0 + (bufo)); ASYNC16(gB1, lB1 + (bufo));                   \
    gA0 += 64; gA1 += 64; gB0 += 64; gB1 += 64;

  // prologue: stage K-tile 0 into buffer 0
  STAGE(0)

  #pragma unroll
  for (int it = 0; it < 4; ++it) {
    __syncthreads();  // drains loads for buffer `cur` (issued one iter ago)
    const int co = (it & 1) * 8192;
    const int no = co ^ 8192;
    if (it < 3) { STAGE(no) }
    union frag { int4 h[2]; intx8 v; };
    frag aF[4], bF[4];
    #pragma unroll
    for (int i = 0; i < 4; ++i) {
      aF[i].h[0] = *(const int4*)(shA + co + aRow + i * 1024);
      aF[i].h[1] = aF[i].h[0];   // fp4 uses low 4 regs; keep upper defined
    }
    #pragma unroll
    for (int j = 0; j < 4; ++j) {
      bF[j].h[0] = *(const int4*)(shB + co + bRow + j * 1024);
      bF[j].h[1] = bF[j].h[0];
    }
    #pragma unroll
    for (int i = 0; i < 4; ++i)
      #pragma unroll
      for (int j = 0; j < 4; ++j)
        // cbsz=4 (A=fp4), blgp=4 (B=fp4); scales = E8M0 127 = 1.0
        acc[i][j] = __builtin_amdgcn_mfma_scale_f32_16x16x128_f8f6f4(
            aF[i].v, bF[j].v, acc[i][j], 4, 4, 0, 127, 0, 127);
  }
  #undef STAGE

  // ---- epilogue (identical structure to R13/R14). C/D: col=lo, row=quad*4+r.
  // acc holds 4096*sim -> logit = acc*10/4096.
  const float LS = 10.0f / 4096.0f;
  float rs[4][4];
  float cs[4];
  #pragma unroll
  for (int i = 0; i < 4; ++i)
    #pragma unroll
    for (int r = 0; r < 4; ++r) rs[i][r] = 0.f;
  #pragma unroll
  for (int j = 0; j < 4; ++j) cs[j] = 0.f;

  #pragma unroll
  for (int i = 0; i < 4; ++i)
    #pragma unroll
    for (int j = 0; j < 4; ++j)
      #pragma unroll
      for (int r = 0; r < 4; ++r) {
        const float e = __expf(acc[i][j][r] * LS - 10.0f);
        rs[i][r] += e;
        cs[j] += e;
      }

  // block-local diagonal lanes: wm==wn, lo == quad*4 + r  (i.e. quad == lo>>2)
  if (wm == wn && quad == (lo >> 2)) {
    const int r = lo & 3;
    if (diag) {  // self-similarity: remove exp from both row and col sums
      #pragma unroll
      for (int i = 0; i < 4; ++i) {
        const float e = __expf(acc[i][i][r] * LS - 10.0f);
        rs[i][r] -= e;
        cs[i] -= e;
      }
    }
    if (posb) {  // positives: col == row + BATCH
      #pragma unroll
      for (int i = 0; i < 4; ++i) {
        const int row = tileRow + wm * 64 + i * 16 + lo;
        const float v = acc[i][i][r] * LS;
        P[row] = v;
        P[row + BATCH] = v;
      }
    }
  }

  // row sums: reduce across the 16 column-lanes (low 4 lane bits)
  #pragma unroll
  for (int m = 1; m < 16; m <<= 1) {
    #pragma unroll
    for (int i = 0; i < 4; ++i)
      #pragma unroll
      for (int r = 0; r < 4; ++r)
        rs[i][r] += __shfl_xor(rs[i][r], m, 64);
  }
  if (lo == 0) {
    #pragma unroll
    for (int i = 0; i < 4; ++i)
      #pragma unroll
      for (int r = 0; r < 4; ++r)
        redR[wn][wm * 64 + i * 16 + quad * 4 + r] = rs[i][r];
  }
  // col sums: reduce across the 4 quads (lane bits 4,5)
  #pragma unroll
  for (int m = 16; m < 64; m <<= 1) {
    #pragma unroll
    for (int j = 0; j < 4; ++j) cs[j] += __shfl_xor(cs[j], m, 64);
  }
  if (quad == 0) {
    #pragma unroll
    for (int j = 0; j < 4; ++j)
      redC[wm][wn * 64 + j * 16 + lo] = cs[j];
  }
  __syncthreads();
  if (t < 128) {
    atomicAdd(&S[tileRow + t], redR[0][t] + redR[1][t]);
  } else if (!diag) {
    const int c = t - 128;
    atomicAdd(&S[tileCol + c], redC[0][c] + redC[1][c]);
  }
  // waves retire here, fire-and-forget on the atomics (no drain — critical).
}

// ---------------------------------------------------------------- final loss
// 32 blocks x 256 threads, 1 element/thread; partial per block, one float
// atomicAdd into out[0] (zeroed by nrm).
__global__ __launch_bounds__(256) void loss_kernel(const float* __restrict__ S,
                                                   const float* __restrict__ P,
                                                   float* __restrict__ out) {
  const int i = blockIdx.x * 256 + threadIdx.x;
  float a = 10.0f + logf(S[i]) - P[i];
  #pragma unroll
  for (int m = 1; m < 64; m <<= 1) a += __shfl_xor(a, m, 64);
  __shared__ float sb[4];
  if ((threadIdx.x & 63) == 0) sb[threadIdx.x >> 6] = a;
  __syncthreads();
  if (threadIdx.x == 0)
    atomicAdd(out, (sb[0] + sb[1] + sb[2] + sb[3]) * (1.0f / (float)NTOT));
}

extern "C" void kernel_launch(void* const* d_in, const int* in_sizes, int n_in,
                              void* d_out, int out_size, void* d_ws, size_t ws_size,
                              hipStream_t stream) {
  const float* zi = (const float*)d_in[0];
  const float* zj = (const float*)d_in[1];
  unsigned char* zn = (unsigned char*)d_ws;                    // 8192*256 fp4 = 2 MB
  float*  S  = (float*)((char*)d_ws + (size_t)NTOT * DIM * 2); // (offset kept)
  float*  P  = S + NTOT;                                       // 32 KB
  float*  out = (float*)d_out;

  nrm_kernel<<<NTOT / 4, 256, 0, stream>>>(zi, zj, zn, S, out);
  simsum_kernel<<<NBLK, 256, 0, stream>>>(zn, S, P);
  loss_kernel<<<NTOT / 256, 256, 0, stream>>>(S, P, out);
}